// Round 1
// baseline (435.145 us; speedup 1.0000x reference)
//
#include <hip/hip_runtime.h>
#include <math.h>

#define NB 16
#define NN 1000
#define NT 16000          // NB*NN total nodes
#define NE 16000          // edges per graph
#define EBASE 256000      // NB*NE
#define ETOT 272000       // EBASE + NT self loops
#define F1 1024           // H1*C1
#define EMB 64
#define HID 128

// ---- scrambled edge mapping (faithful to reference row-major reshape) ----
__device__ __forceinline__ int src_of(const int* ei, int j) {
    if (j < EBASE) return ei[j] + (j / 32000) * 1000;
    return j - EBASE;
}
__device__ __forceinline__ int dst_of(const int* ei, int j) {
    if (j < EBASE) return ei[EBASE + j] + (8 + j / 32000) * 1000;
    return j - EBASE;
}

__device__ __forceinline__ float lrelu02(float r) { return r >= 0.f ? r : 0.2f * r; }
__device__ __forceinline__ float elu1(float v)    { return v > 0.f ? v : expm1f(v); }

// ---- precontract attention vectors: wa[3][8] for conv1, v2[1024] for conv2 ----
__global__ void k_precompute(const float* __restrict__ W1, const float* __restrict__ as1w,
                             const float* __restrict__ ad1w, const float* __restrict__ W2,
                             const float* __restrict__ as2w, const float* __restrict__ ad2w,
                             float* wa_s, float* wa_d, float* v2s, float* v2d) {
    int t = threadIdx.x;
    // v2s[k] = sum_c W2[k][c]*att_src2[c]
    float s = 0.f, d = 0.f;
    for (int c = 0; c < EMB; ++c) {
        float w = W2[t * EMB + c];
        s += w * as2w[c]; d += w * ad2w[c];
    }
    v2s[t] = s; v2d[t] = d;
    if (t < 24) {
        int k = t / 8, h = t % 8;
        float ss = 0.f, dd = 0.f;
        for (int c = 0; c < 128; ++c) {
            float w = W1[k * F1 + h * 128 + c];
            ss += w * as1w[h * 128 + c];
            dd += w * ad1w[h * 128 + c];
        }
        wa_s[k * 8 + h] = ss; wa_d[k * 8 + h] = dd;
    }
}

// ---- build x[NT][3] and per-node attention logits a_src1/a_dst1 [NT][8] ----
__global__ void k_nodeinit(const float* __restrict__ actions, const float* __restrict__ nf,
                           const float* __restrict__ wa_s, const float* __restrict__ wa_d,
                           float* __restrict__ x, float* __restrict__ as1, float* __restrict__ ad1) {
    int n = blockIdx.x * blockDim.x + threadIdx.x;
    if (n >= NT) return;
    float x0 = actions[n * 2 + 0];
    float x1v = actions[n * 2 + 1];
    float x2v = nf[n];            // [B,1,N] flat == [B*N]
    x[n * 3 + 0] = x0; x[n * 3 + 1] = x1v; x[n * 3 + 2] = x2v;
    #pragma unroll
    for (int h = 0; h < 8; ++h) {
        as1[n * 8 + h] = x0 * wa_s[h] + x1v * wa_s[8 + h] + x2v * wa_s[16 + h];
        ad1[n * 8 + h] = x0 * wa_d[h] + x1v * wa_d[8 + h] + x2v * wa_d[16 + h];
    }
}

// ---- CSR by dst: count / scan / fill ----
__global__ void k_count(const int* __restrict__ ei, int* __restrict__ counts) {
    int j = blockIdx.x * blockDim.x + threadIdx.x;
    if (j >= ETOT) return;
    atomicAdd(&counts[dst_of(ei, j)], 1);
}

__global__ __launch_bounds__(1024) void k_scan(const int* __restrict__ counts,
                                               int* __restrict__ offs, int* __restrict__ cursor) {
    __shared__ int lds[1024];
    int t = threadIdx.x;
    int base = t * 16;
    int local[16];
    int mysum = 0;
    #pragma unroll
    for (int i = 0; i < 16; ++i) {
        int idx = base + i;
        int c = (idx < NT) ? counts[idx] : 0;
        local[i] = c; mysum += c;
    }
    lds[t] = mysum;
    __syncthreads();
    for (int off = 1; off < 1024; off <<= 1) {
        int v = (t >= off) ? lds[t - off] : 0;
        __syncthreads();
        lds[t] += v;
        __syncthreads();
    }
    int run = lds[t] - mysum;   // exclusive prefix
    #pragma unroll
    for (int i = 0; i < 16; ++i) {
        int idx = base + i;
        if (idx < NT) { offs[idx] = run; cursor[idx] = run; run += local[i]; }
    }
    if (t == 1023) offs[NT] = lds[1023];
}

__global__ void k_fill(const int* __restrict__ ei, int* __restrict__ cursor, int* __restrict__ esrc) {
    int j = blockIdx.x * blockDim.x + threadIdx.x;
    if (j >= ETOT) return;
    int dv = dst_of(ei, j);
    int pos = atomicAdd(&cursor[dv], 1);
    esrc[pos] = src_of(ei, j);
}

// ---- conv1: per-node segment softmax over 3-dim x, then @W1 + b1 + elu -> x1[NT][1024]
//      fused: a2s/a2d = x1row . v2s/v2d for conv2 attention
__global__ __launch_bounds__(64) void k_conv1(
    const int* __restrict__ offs, const int* __restrict__ esrc, const float* __restrict__ x,
    const float* __restrict__ as1, const float* __restrict__ ad1,
    const float* __restrict__ W1, const float* __restrict__ b1,
    const float* __restrict__ v2s, const float* __restrict__ v2d,
    float* __restrict__ x1, float* __restrict__ a2s, float* __restrict__ a2d) {
    int d = blockIdx.x;
    int lane = threadIdx.x;
    int off = offs[d], end = offs[d + 1];

    float ad[8];
    #pragma unroll
    for (int h = 0; h < 8; ++h) ad[h] = ad1[d * 8 + h];

    // pass 1: per-head max
    float m[8];
    #pragma unroll
    for (int h = 0; h < 8; ++h) m[h] = -1e30f;
    for (int e = off + lane; e < end; e += 64) {
        int s = esrc[e];
        #pragma unroll
        for (int h = 0; h < 8; ++h)
            m[h] = fmaxf(m[h], lrelu02(as1[s * 8 + h] + ad[h]));
    }
    #pragma unroll
    for (int st = 1; st < 64; st <<= 1) {
        #pragma unroll
        for (int h = 0; h < 8; ++h) m[h] = fmaxf(m[h], __shfl_xor(m[h], st, 64));
    }

    // pass 2: denom + alpha-weighted x sums
    float den[8], sx0[8], sx1[8], sx2[8];
    #pragma unroll
    for (int h = 0; h < 8; ++h) { den[h] = 0.f; sx0[h] = 0.f; sx1[h] = 0.f; sx2[h] = 0.f; }
    for (int e = off + lane; e < end; e += 64) {
        int s = esrc[e];
        float xv0 = x[s * 3 + 0], xv1 = x[s * 3 + 1], xv2 = x[s * 3 + 2];
        #pragma unroll
        for (int h = 0; h < 8; ++h) {
            float ea = __expf(lrelu02(as1[s * 8 + h] + ad[h]) - m[h]);
            den[h] += ea; sx0[h] += ea * xv0; sx1[h] += ea * xv1; sx2[h] += ea * xv2;
        }
    }
    #pragma unroll
    for (int st = 1; st < 64; st <<= 1) {
        #pragma unroll
        for (int h = 0; h < 8; ++h) {
            den[h] += __shfl_xor(den[h], st, 64);
            sx0[h] += __shfl_xor(sx0[h], st, 64);
            sx1[h] += __shfl_xor(sx1[h], st, 64);
            sx2[h] += __shfl_xor(sx2[h], st, 64);
        }
    }
    #pragma unroll
    for (int h = 0; h < 8; ++h) {
        float inv = 1.f / den[h];
        sx0[h] *= inv; sx1[h] *= inv; sx2[h] *= inv;
    }

    // epilogue: out1 = xs @ W1 (per head slice) + b1, elu; fuse conv2 logits
    float acc_s = 0.f, acc_d = 0.f;
    #pragma unroll
    for (int i = 0; i < 16; ++i) {
        int idx = i * 64 + lane;        // coalesced
        int h = idx >> 7;
        float v = sx0[h] * W1[idx] + sx1[h] * W1[F1 + idx] + sx2[h] * W1[2 * F1 + idx] + b1[idx];
        v = elu1(v);
        x1[d * F1 + idx] = v;
        acc_s += v * v2s[idx];
        acc_d += v * v2d[idx];
    }
    #pragma unroll
    for (int st = 1; st < 64; st <<= 1) {
        acc_s += __shfl_xor(acc_s, st, 64);
        acc_d += __shfl_xor(acc_d, st, 64);
    }
    if (lane == 0) { a2s[d] = acc_s; a2d[d] = acc_d; }
}

// ---- h2 = x1 @ W2 : [16000,1024]@[1024,64] ----
__global__ __launch_bounds__(256) void k_gemm_h2(const float* __restrict__ x1,
                                                 const float* __restrict__ W2,
                                                 float* __restrict__ h2) {
    __shared__ float xs[16][64];
    __shared__ float wt[64][64];
    int t = threadIdx.x;
    int c = t & 63, r0 = t >> 6;     // c: out col, rows r0, r0+4, r0+8, r0+12
    int row0 = blockIdx.x * 16;
    float acc[4] = {0.f, 0.f, 0.f, 0.f};
    for (int k0 = 0; k0 < F1; k0 += 64) {
        for (int idx = t; idx < 16 * 64; idx += 256) {
            int rr = idx >> 6, kk = idx & 63;
            xs[rr][kk] = x1[(row0 + rr) * F1 + k0 + kk];
        }
        for (int idx = t; idx < 64 * 64; idx += 256)
            wt[idx >> 6][idx & 63] = W2[k0 * EMB + idx];
        __syncthreads();
        #pragma unroll
        for (int kk = 0; kk < 64; ++kk) {
            float w = wt[kk][c];
            acc[0] += xs[r0][kk] * w;
            acc[1] += xs[r0 + 4][kk] * w;
            acc[2] += xs[r0 + 8][kk] * w;
            acc[3] += xs[r0 + 12][kk] * w;
        }
        __syncthreads();
    }
    #pragma unroll
    for (int i = 0; i < 4; ++i)
        h2[(row0 + r0 + 4 * i) * EMB + c] = acc[i];
}

// ---- conv2: segment softmax (1 head) + 64-dim message agg + b2 + elu -> x2[NT][64]
__global__ __launch_bounds__(64) void k_conv2(
    const int* __restrict__ offs, const int* __restrict__ esrc, const float* __restrict__ h2,
    const float* __restrict__ a2s, const float* __restrict__ a2d, const float* __restrict__ b2,
    float* __restrict__ x2) {
    int d = blockIdx.x, lane = threadIdx.x;
    int off = offs[d], end = offs[d + 1];
    float adv = a2d[d];
    float m = -1e30f;
    for (int e = off + lane; e < end; e += 64)
        m = fmaxf(m, lrelu02(a2s[esrc[e]] + adv));
    #pragma unroll
    for (int st = 1; st < 64; st <<= 1) m = fmaxf(m, __shfl_xor(m, st, 64));

    float den = 0.f, acc = 0.f;
    for (int e = off; e < end; ++e) {      // all lanes walk all edges; lane owns channel
        int s = esrc[e];
        float ea = __expf(lrelu02(a2s[s] + adv) - m);
        den += ea;
        acc += ea * h2[s * EMB + lane];
    }
    float v = acc / den + b2[lane];
    x2[d * EMB + lane] = elu1(v);
}

// ---- MLP layer 1: y1acc += x2_flat[16,64000] @ mlp_w1[64000,128] (K-slab partials) ----
__global__ __launch_bounds__(256) void k_mlp1(const float* __restrict__ x2,
                                              const float* __restrict__ w1,
                                              float* __restrict__ y1acc) {
    int t = threadIdx.x;
    int j = t & 127, half = t >> 7;
    int k0 = blockIdx.x * 250;
    float acc[8] = {0.f, 0.f, 0.f, 0.f, 0.f, 0.f, 0.f, 0.f};
    for (int k = 0; k < 250; ++k) {
        float w = w1[(k0 + k) * HID + j];
        #pragma unroll
        for (int q = 0; q < 8; ++q)
            acc[q] += x2[(half * 8 + q) * 64000 + k0 + k] * w;
    }
    #pragma unroll
    for (int q = 0; q < 8; ++q)
        atomicAdd(&y1acc[(half * 8 + q) * HID + j], acc[q]);
}

// ---- MLP layer 2: y2 = relu(relu(y1acc+b1) @ w2 + b2) ----
__global__ __launch_bounds__(256) void k_mlp2(const float* __restrict__ y1acc,
                                              const float* __restrict__ b1m,
                                              const float* __restrict__ w2,
                                              const float* __restrict__ b2m,
                                              float* __restrict__ y2) {
    __shared__ float y1[NB * HID];
    int t = threadIdx.x;
    for (int idx = t; idx < NB * HID; idx += 256)
        y1[idx] = fmaxf(y1acc[idx] + b1m[idx & 127], 0.f);
    __syncthreads();
    #pragma unroll
    for (int i = 0; i < 8; ++i) {
        int o = t + i * 256;
        int b = o >> 7, j = o & 127;
        float acc = b2m[j];
        for (int k = 0; k < HID; ++k) acc += y1[b * HID + k] * w2[k * HID + j];
        y2[o] = fmaxf(acc, 0.f);
    }
}

// ---- output: sigmoid(y2 @ out_w + out_b) -> [16,1000] ----
__global__ __launch_bounds__(64) void k_out(const float* __restrict__ y2,
                                            const float* __restrict__ ow,
                                            const float* __restrict__ ob,
                                            float* __restrict__ out) {
    int n = blockIdx.x * 64 + threadIdx.x;
    if (n >= NN) return;
    float acc[NB];
    #pragma unroll
    for (int b = 0; b < NB; ++b) acc[b] = 0.f;
    for (int jj = 0; jj < HID; ++jj) {
        float w = ow[jj * NN + n];
        #pragma unroll
        for (int b = 0; b < NB; ++b) acc[b] += y2[b * HID + jj] * w;
    }
    float obv = ob[n];
    #pragma unroll
    for (int b = 0; b < NB; ++b)
        out[b * NN + n] = 1.f / (1.f + __expf(-(acc[b] + obv)));
}

extern "C" void kernel_launch(void* const* d_in, const int* in_sizes, int n_in,
                              void* d_out, int out_size, void* d_ws, size_t ws_size,
                              hipStream_t stream) {
    const float* actions = (const float*)d_in[0];
    const float* nf      = (const float*)d_in[1];
    const int*   ei      = (const int*)d_in[2];
    const float* W1      = (const float*)d_in[3];
    const float* as1w    = (const float*)d_in[4];
    const float* ad1w    = (const float*)d_in[5];
    const float* b1      = (const float*)d_in[6];
    const float* W2      = (const float*)d_in[7];
    const float* as2w    = (const float*)d_in[8];
    const float* ad2w    = (const float*)d_in[9];
    const float* b2      = (const float*)d_in[10];
    const float* mw1     = (const float*)d_in[11];
    const float* mb1     = (const float*)d_in[12];
    const float* mw2     = (const float*)d_in[13];
    const float* mb2     = (const float*)d_in[14];
    const float* ow      = (const float*)d_in[15];
    const float* ob      = (const float*)d_in[16];
    float* out = (float*)d_out;

    // workspace carve (~77 MB)
    float* f = (float*)d_ws;
    float* x    = f;  f += NT * 3;
    float* x1   = f;  f += (size_t)NT * F1;
    float* h2   = f;  f += NT * EMB;
    float* x2   = f;  f += NT * EMB;
    float* as1  = f;  f += NT * 8;
    float* ad1  = f;  f += NT * 8;
    float* a2s  = f;  f += NT;
    float* a2d  = f;  f += NT;
    float* wa_s = f;  f += 32;
    float* wa_d = f;  f += 32;
    float* v2s  = f;  f += F1;
    float* v2d  = f;  f += F1;
    float* y1acc= f;  f += NB * HID;
    float* y2   = f;  f += NB * HID;
    int* ip = (int*)f;
    int* counts = ip; ip += NT;
    int* offs   = ip; ip += NT + 1;
    int* cursor = ip; ip += NT;
    int* esrc   = ip; ip += ETOT;

    hipMemsetAsync(counts, 0, NT * sizeof(int), stream);
    hipMemsetAsync(y1acc, 0, NB * HID * sizeof(float), stream);

    k_precompute<<<1, 1024, 0, stream>>>(W1, as1w, ad1w, W2, as2w, ad2w, wa_s, wa_d, v2s, v2d);
    k_nodeinit<<<(NT + 255) / 256, 256, 0, stream>>>(actions, nf, wa_s, wa_d, x, as1, ad1);
    k_count<<<(ETOT + 255) / 256, 256, 0, stream>>>(ei, counts);
    k_scan<<<1, 1024, 0, stream>>>(counts, offs, cursor);
    k_fill<<<(ETOT + 255) / 256, 256, 0, stream>>>(ei, cursor, esrc);
    k_conv1<<<NT, 64, 0, stream>>>(offs, esrc, x, as1, ad1, W1, b1, v2s, v2d, x1, a2s, a2d);
    k_gemm_h2<<<NT / 16, 256, 0, stream>>>(x1, W2, h2);
    k_conv2<<<NT, 64, 0, stream>>>(offs, esrc, h2, a2s, a2d, b2, x2);
    k_mlp1<<<256, 256, 0, stream>>>(x2, mw1, y1acc);
    k_mlp2<<<1, 256, 0, stream>>>(y1acc, mb1, mw2, mb2, y2);
    k_out<<<(NN + 63) / 64, 64, 0, stream>>>(y2, ow, ob, out);
}

// Round 3
// 358.012 us; speedup vs baseline: 1.2154x; 1.2154x over previous
//
#include <hip/hip_runtime.h>
#include <math.h>

#define NB 16
#define NN 1000
#define NT 16000          // NB*NN total nodes
#define NE 16000          // edges per graph
#define EBASE 256000      // NB*NE
#define ETOT 272000       // EBASE + NT self loops
#define F1 1024           // H1*C1
#define EMB 64
#define HID 128

typedef unsigned short ushort_t;
typedef unsigned int uint_t;
typedef __attribute__((ext_vector_type(8))) _Float16 half8;
typedef __attribute__((ext_vector_type(4))) float float4_;

// ---- scrambled edge mapping (faithful to reference row-major reshape) ----
__device__ __forceinline__ int src_of(const int* ei, int j) {
    if (j < EBASE) return ei[j] + (j / 32000) * 1000;
    return j - EBASE;
}
__device__ __forceinline__ int dst_of(const int* ei, int j) {
    if (j < EBASE) return ei[EBASE + j] + (8 + j / 32000) * 1000;
    return j - EBASE;
}

__device__ __forceinline__ float lrelu02(float r) { return r >= 0.f ? r : 0.2f * r; }
__device__ __forceinline__ float elu1(float v)    { return v > 0.f ? v : expm1f(v); }
__device__ __forceinline__ ushort_t f2h(float f) {
    _Float16 h = (_Float16)f;           // v_cvt_f16_f32, RTE
    union { _Float16 h; ushort_t u; } c; c.h = h; return c.u;
}

// ---- precontract attention vectors: wa[3][8] for conv1, v2[1024] for conv2 ----
__global__ void k_precompute(const float* __restrict__ W1, const float* __restrict__ as1w,
                             const float* __restrict__ ad1w, const float* __restrict__ W2,
                             const float* __restrict__ as2w, const float* __restrict__ ad2w,
                             float* wa_s, float* wa_d, float* v2s, float* v2d) {
    int t = threadIdx.x;
    float s = 0.f, d = 0.f;
    for (int c = 0; c < EMB; ++c) {
        float w = W2[t * EMB + c];
        s += w * as2w[c]; d += w * ad2w[c];
    }
    v2s[t] = s; v2d[t] = d;
    if (t < 24) {
        int k = t / 8, h = t % 8;
        float ss = 0.f, dd = 0.f;
        for (int c = 0; c < 128; ++c) {
            float w = W1[k * F1 + h * 128 + c];
            ss += w * as1w[h * 128 + c];
            dd += w * ad1w[h * 128 + c];
        }
        wa_s[k * 8 + h] = ss; wa_d[k * 8 + h] = dd;
    }
}

// ---- W2 transpose + fp16 cast: w2t[n][k], n<64, k<1024 ----
__global__ __launch_bounds__(256) void k_w2t(const float* __restrict__ W2,
                                             ushort_t* __restrict__ w2t) {
    __shared__ float tile[64][65];
    int k0 = blockIdx.x * 64;
    int t = threadIdx.x;
    int c = t & 63, g = t >> 6;
    for (int r = g; r < 64; r += 4)
        tile[r][c] = W2[(size_t)(k0 + r) * 64 + c];      // coalesced read
    __syncthreads();
    int kk = t & 63, g2 = t >> 6;
    for (int n = g2; n < 64; n += 4)
        w2t[(size_t)n * 1024 + k0 + kk] = f2h(tile[kk][n]);  // coalesced write
}

// ---- build x[NT][3] and per-node attention logits a_src1/a_dst1 [NT][8] ----
__global__ void k_nodeinit(const float* __restrict__ actions, const float* __restrict__ nf,
                           const float* __restrict__ wa_s, const float* __restrict__ wa_d,
                           float* __restrict__ x, float* __restrict__ as1, float* __restrict__ ad1) {
    int n = blockIdx.x * blockDim.x + threadIdx.x;
    if (n >= NT) return;
    float x0 = actions[n * 2 + 0];
    float x1v = actions[n * 2 + 1];
    float x2v = nf[n];
    x[n * 3 + 0] = x0; x[n * 3 + 1] = x1v; x[n * 3 + 2] = x2v;
    #pragma unroll
    for (int h = 0; h < 8; ++h) {
        as1[n * 8 + h] = x0 * wa_s[h] + x1v * wa_s[8 + h] + x2v * wa_s[16 + h];
        ad1[n * 8 + h] = x0 * wa_d[h] + x1v * wa_d[8 + h] + x2v * wa_d[16 + h];
    }
}

// ---- CSR by dst: count / scan / fill ----
__global__ void k_count(const int* __restrict__ ei, int* __restrict__ counts) {
    int j = blockIdx.x * blockDim.x + threadIdx.x;
    if (j >= ETOT) return;
    atomicAdd(&counts[dst_of(ei, j)], 1);
}

__global__ __launch_bounds__(1024) void k_scan(const int* __restrict__ counts,
                                               int* __restrict__ offs, int* __restrict__ cursor) {
    __shared__ int lds[1024];
    int t = threadIdx.x;
    int base = t * 16;
    int local[16];
    int mysum = 0;
    #pragma unroll
    for (int i = 0; i < 16; ++i) {
        int idx = base + i;
        int c = (idx < NT) ? counts[idx] : 0;
        local[i] = c; mysum += c;
    }
    lds[t] = mysum;
    __syncthreads();
    for (int off = 1; off < 1024; off <<= 1) {
        int v = (t >= off) ? lds[t - off] : 0;
        __syncthreads();
        lds[t] += v;
        __syncthreads();
    }
    int run = lds[t] - mysum;
    #pragma unroll
    for (int i = 0; i < 16; ++i) {
        int idx = base + i;
        if (idx < NT) { offs[idx] = run; cursor[idx] = run; run += local[i]; }
    }
    if (t == 1023) offs[NT] = lds[1023];
}

__global__ void k_fill(const int* __restrict__ ei, int* __restrict__ cursor, int* __restrict__ esrc) {
    int j = blockIdx.x * blockDim.x + threadIdx.x;
    if (j >= ETOT) return;
    int dv = dst_of(ei, j);
    int pos = atomicAdd(&cursor[dv], 1);
    esrc[pos] = src_of(ei, j);
}

// ---- conv1: segment softmax over 3-dim x, @W1 + b1 + elu -> x1 (fp16) ----
__global__ __launch_bounds__(64) void k_conv1(
    const int* __restrict__ offs, const int* __restrict__ esrc, const float* __restrict__ x,
    const float* __restrict__ as1, const float* __restrict__ ad1,
    const float* __restrict__ W1, const float* __restrict__ b1,
    const float* __restrict__ v2s, const float* __restrict__ v2d,
    ushort_t* __restrict__ x1h, float* __restrict__ a2s, float* __restrict__ a2d) {
    int d = blockIdx.x;
    int lane = threadIdx.x;
    int off = offs[d], end = offs[d + 1];

    float ad[8];
    #pragma unroll
    for (int h = 0; h < 8; ++h) ad[h] = ad1[d * 8 + h];

    float m[8];
    #pragma unroll
    for (int h = 0; h < 8; ++h) m[h] = -1e30f;
    for (int e = off + lane; e < end; e += 64) {
        int s = esrc[e];
        #pragma unroll
        for (int h = 0; h < 8; ++h)
            m[h] = fmaxf(m[h], lrelu02(as1[s * 8 + h] + ad[h]));
    }
    #pragma unroll
    for (int st = 1; st < 64; st <<= 1) {
        #pragma unroll
        for (int h = 0; h < 8; ++h) m[h] = fmaxf(m[h], __shfl_xor(m[h], st, 64));
    }

    float den[8], sx0[8], sx1[8], sx2[8];
    #pragma unroll
    for (int h = 0; h < 8; ++h) { den[h] = 0.f; sx0[h] = 0.f; sx1[h] = 0.f; sx2[h] = 0.f; }
    for (int e = off + lane; e < end; e += 64) {
        int s = esrc[e];
        float xv0 = x[s * 3 + 0], xv1 = x[s * 3 + 1], xv2 = x[s * 3 + 2];
        #pragma unroll
        for (int h = 0; h < 8; ++h) {
            float ea = __expf(lrelu02(as1[s * 8 + h] + ad[h]) - m[h]);
            den[h] += ea; sx0[h] += ea * xv0; sx1[h] += ea * xv1; sx2[h] += ea * xv2;
        }
    }
    #pragma unroll
    for (int st = 1; st < 64; st <<= 1) {
        #pragma unroll
        for (int h = 0; h < 8; ++h) {
            den[h] += __shfl_xor(den[h], st, 64);
            sx0[h] += __shfl_xor(sx0[h], st, 64);
            sx1[h] += __shfl_xor(sx1[h], st, 64);
            sx2[h] += __shfl_xor(sx2[h], st, 64);
        }
    }
    #pragma unroll
    for (int h = 0; h < 8; ++h) {
        float inv = 1.f / den[h];
        sx0[h] *= inv; sx1[h] *= inv; sx2[h] *= inv;
    }

    // epilogue: per i (=head), lane covers channels 2*lane, 2*lane+1
    float acc_s = 0.f, acc_d = 0.f;
    uint_t* x1row = (uint_t*)(x1h + (size_t)d * F1);
    #pragma unroll
    for (int i = 0; i < 8; ++i) {
        int idx = i * 128 + lane * 2;
        float v0 = sx0[i] * W1[idx]     + sx1[i] * W1[F1 + idx]     + sx2[i] * W1[2 * F1 + idx]     + b1[idx];
        float v1 = sx0[i] * W1[idx + 1] + sx1[i] * W1[F1 + idx + 1] + sx2[i] * W1[2 * F1 + idx + 1] + b1[idx + 1];
        v0 = elu1(v0); v1 = elu1(v1);
        acc_s += v0 * v2s[idx] + v1 * v2s[idx + 1];
        acc_d += v0 * v2d[idx] + v1 * v2d[idx + 1];
        x1row[idx >> 1] = (uint_t)f2h(v0) | ((uint_t)f2h(v1) << 16);
    }
    #pragma unroll
    for (int st = 1; st < 64; st <<= 1) {
        acc_s += __shfl_xor(acc_s, st, 64);
        acc_d += __shfl_xor(acc_d, st, 64);
    }
    if (lane == 0) { a2s[d] = acc_s; a2d[d] = acc_d; }
}

// ---- h2 = x1 @ W2 via fp16 MFMA: [16000,1024]@[1024,64] -> fp32 ----
// A frag: lane holds x1[row0+ (l&15)][ks + (l>>4)*8 .. +7]   (8 k-consecutive fp16)
// B frag: lane holds W2t[n0 + (l&15)][ks + (l>>4)*8 .. +7]
// C/D:    col = l&15, row = (l>>4)*4 + reg                    (m89-verified)
__global__ __launch_bounds__(256) void k_h2(const ushort_t* __restrict__ x1h,
                                            const ushort_t* __restrict__ w2t,
                                            float* __restrict__ h2) {
    int wave = threadIdx.x >> 6, lane = threadIdx.x & 63;
    int row0 = blockIdx.x * 64 + wave * 16;
    int mrow = lane & 15, kg = lane >> 4;
    const ushort_t* ap = x1h + (size_t)(row0 + mrow) * F1 + kg * 8;
    const ushort_t* bp = w2t + (size_t)mrow * F1 + kg * 8;   // +n0*F1 per tile
    float4_ acc[4] = {{0,0,0,0},{0,0,0,0},{0,0,0,0},{0,0,0,0}};
    #pragma unroll 4
    for (int ks = 0; ks < F1; ks += 32) {
        half8 a = *(const half8*)(ap + ks);
        #pragma unroll
        for (int t = 0; t < 4; ++t) {
            half8 b = *(const half8*)(bp + (size_t)t * 16 * F1 + ks);
            acc[t] = __builtin_amdgcn_mfma_f32_16x16x32_f16(a, b, acc[t], 0, 0, 0);
        }
    }
    int col = lane & 15;
    #pragma unroll
    for (int t = 0; t < 4; ++t) {
        #pragma unroll
        for (int r = 0; r < 4; ++r) {
            int row = kg * 4 + r;
            h2[(size_t)(row0 + row) * EMB + t * 16 + col] = acc[t][r];
        }
    }
}

// ---- conv2: segment softmax (1 head) + 64-ch message agg -> x2t (transposed) ----
// x2t layout: x2t[(n*64+c)*16 + b]  where node d = b*1000+n  (mlp1-friendly)
__global__ __launch_bounds__(64) void k_conv2(
    const int* __restrict__ offs, const int* __restrict__ esrc, const float* __restrict__ h2,
    const float* __restrict__ a2s, const float* __restrict__ a2d, const float* __restrict__ b2,
    float* __restrict__ x2t) {
    int d = blockIdx.x, lane = threadIdx.x;
    int off = offs[d], end = offs[d + 1];
    float adv = a2d[d];

    float m = -1e30f;
    for (int e = off + lane; e < end; e += 64)
        m = fmaxf(m, lrelu02(a2s[esrc[e]] + adv));
    #pragma unroll
    for (int st = 1; st < 64; st <<= 1) m = fmaxf(m, __shfl_xor(m, st, 64));

    float den = 0.f;
    for (int e = off + lane; e < end; e += 64)
        den += __expf(lrelu02(a2s[esrc[e]] + adv) - m);
    #pragma unroll
    for (int st = 1; st < 64; st <<= 1) den += __shfl_xor(den, st, 64);

    // message: 4 edge-groups x 16 channel-groups (float4)
    int eg = lane >> 4, c4 = (lane & 15) * 4;
    float4_ acc = {0.f, 0.f, 0.f, 0.f};
    for (int e = off + eg; e < end; e += 4) {
        int s = esrc[e];
        float ea = __expf(lrelu02(a2s[s] + adv) - m);
        float4_ hv = *(const float4_*)(h2 + (size_t)s * EMB + c4);
        acc.x += ea * hv.x; acc.y += ea * hv.y; acc.z += ea * hv.z; acc.w += ea * hv.w;
    }
    #pragma unroll
    for (int st = 16; st < 64; st <<= 1) {
        acc.x += __shfl_xor(acc.x, st, 64);
        acc.y += __shfl_xor(acc.y, st, 64);
        acc.z += __shfl_xor(acc.z, st, 64);
        acc.w += __shfl_xor(acc.w, st, 64);
    }
    if (eg == 0) {
        float inv = 1.f / den;
        int n = d % NN, b = d / NN;
        #pragma unroll
        for (int q = 0; q < 4; ++q) {
            float v = acc[q] * inv + b2[c4 + q];
            x2t[(size_t)(n * EMB + c4 + q) * NB + b] = elu1(v);
        }
    }
}

// ---- MLP1: y1part[p] += x2t-slab @ mlp_w1-slab; x2t reads are wave-uniform ----
__global__ __launch_bounds__(128) void k_mlp1(const float* __restrict__ x2t,
                                              const float* __restrict__ w1,
                                              float* __restrict__ y1part) {
    int t = threadIdx.x;
    int k0 = blockIdx.x * 250;
    float acc[16];
    #pragma unroll
    for (int b = 0; b < 16; ++b) acc[b] = 0.f;
    const float* wp = w1 + (size_t)k0 * HID + t;
    #pragma unroll 2
    for (int k = 0; k < 250; ++k) {
        float w = wp[(size_t)k * HID];
        const float* xr = x2t + (size_t)(k0 + k) * NB;   // uniform -> s_load
        #pragma unroll
        for (int b = 0; b < 16; ++b) acc[b] += xr[b] * w;
    }
    float* yp = y1part + (size_t)(blockIdx.x & 15) * (NB * HID);
    #pragma unroll
    for (int b = 0; b < 16; ++b) atomicAdd(&yp[b * HID + t], acc[b]);
}

// ---- MLP2: reduce 16 partials, relu, then y2 = relu(y1 @ w2 + b2) ----
__global__ __launch_bounds__(256) void k_mlp2(const float* __restrict__ y1part,
                                              const float* __restrict__ b1m,
                                              const float* __restrict__ w2,
                                              const float* __restrict__ b2m,
                                              float* __restrict__ y2) {
    __shared__ float y1[NB * HID];
    int t = threadIdx.x;
    for (int idx = t; idx < NB * HID; idx += 256) {
        float s = b1m[idx & 127];
        #pragma unroll
        for (int p = 0; p < 16; ++p) s += y1part[p * (NB * HID) + idx];
        y1[idx] = fmaxf(s, 0.f);
    }
    __syncthreads();
    #pragma unroll
    for (int i = 0; i < 8; ++i) {
        int o = t + i * 256;
        int b = o >> 7, j = o & 127;
        float acc = b2m[j];
        for (int k = 0; k < HID; ++k) acc += y1[b * HID + k] * w2[k * HID + j];
        y2[o] = fmaxf(acc, 0.f);
    }
}

// ---- output: sigmoid(y2 @ out_w + out_b) -> [16,1000] ----
__global__ __launch_bounds__(64) void k_out(const float* __restrict__ y2,
                                            const float* __restrict__ ow,
                                            const float* __restrict__ ob,
                                            float* __restrict__ out) {
    int n = blockIdx.x * 64 + threadIdx.x;
    if (n >= NN) return;
    float acc[NB];
    #pragma unroll
    for (int b = 0; b < NB; ++b) acc[b] = 0.f;
    for (int jj = 0; jj < HID; ++jj) {
        float w = ow[jj * NN + n];
        #pragma unroll
        for (int b = 0; b < NB; ++b) acc[b] += y2[b * HID + jj] * w;
    }
    float obv = ob[n];
    #pragma unroll
    for (int b = 0; b < NB; ++b)
        out[b * NN + n] = 1.f / (1.f + __expf(-(acc[b] + obv)));
}

extern "C" void kernel_launch(void* const* d_in, const int* in_sizes, int n_in,
                              void* d_out, int out_size, void* d_ws, size_t ws_size,
                              hipStream_t stream) {
    const float* actions = (const float*)d_in[0];
    const float* nf      = (const float*)d_in[1];
    const int*   ei      = (const int*)d_in[2];
    const float* W1      = (const float*)d_in[3];
    const float* as1w    = (const float*)d_in[4];
    const float* ad1w    = (const float*)d_in[5];
    const float* b1      = (const float*)d_in[6];
    const float* W2      = (const float*)d_in[7];
    const float* as2w    = (const float*)d_in[8];
    const float* ad2w    = (const float*)d_in[9];
    const float* b2      = (const float*)d_in[10];
    const float* mw1     = (const float*)d_in[11];
    const float* mb1     = (const float*)d_in[12];
    const float* mw2     = (const float*)d_in[13];
    const float* mb2     = (const float*)d_in[14];
    const float* ow      = (const float*)d_in[15];
    const float* ob      = (const float*)d_in[16];
    float* out = (float*)d_out;

    // workspace carve (all segments 16B-aligned)
    float* f = (float*)d_ws;
    float* x     = f;  f += NT * 3;
    float* h2    = f;  f += (size_t)NT * EMB;
    float* x2t   = f;  f += (size_t)NT * EMB;
    float* as1   = f;  f += NT * 8;
    float* ad1   = f;  f += NT * 8;
    float* a2s   = f;  f += NT;
    float* a2d   = f;  f += NT;
    float* wa_s  = f;  f += 32;
    float* wa_d  = f;  f += 32;
    float* v2s   = f;  f += F1;
    float* v2d   = f;  f += F1;
    float* y1part= f;  f += 16 * NB * HID;
    float* y2    = f;  f += NB * HID;
    ushort_t* x1h = (ushort_t*)f;
    ushort_t* w2t = x1h + (size_t)NT * F1;
    int* ip = (int*)(w2t + (size_t)EMB * F1);
    int* counts = ip; ip += NT;
    int* offs   = ip; ip += NT + 1;
    int* cursor = ip; ip += NT;
    int* esrc   = ip; ip += ETOT;

    hipMemsetAsync(counts, 0, NT * sizeof(int), stream);
    hipMemsetAsync(y1part, 0, 16 * NB * HID * sizeof(float), stream);

    k_precompute<<<1, 1024, 0, stream>>>(W1, as1w, ad1w, W2, as2w, ad2w, wa_s, wa_d, v2s, v2d);
    k_w2t<<<16, 256, 0, stream>>>(W2, w2t);
    k_nodeinit<<<(NT + 255) / 256, 256, 0, stream>>>(actions, nf, wa_s, wa_d, x, as1, ad1);
    k_count<<<(ETOT + 255) / 256, 256, 0, stream>>>(ei, counts);
    k_scan<<<1, 1024, 0, stream>>>(counts, offs, cursor);
    k_fill<<<(ETOT + 255) / 256, 256, 0, stream>>>(ei, cursor, esrc);
    k_conv1<<<NT, 64, 0, stream>>>(offs, esrc, x, as1, ad1, W1, b1, v2s, v2d, x1h, a2s, a2d);
    k_h2<<<NT / 64, 256, 0, stream>>>(x1h, w2t, h2);
    k_conv2<<<NT, 64, 0, stream>>>(offs, esrc, h2, a2s, a2d, b2, x2t);
    k_mlp1<<<256, 128, 0, stream>>>(x2t, mw1, y1part);
    k_mlp2<<<1, 256, 0, stream>>>(y1part, mb1, mw2, mb2, y2);
    k_out<<<(NN + 63) / 64, 64, 0, stream>>>(y2, ow, ob, out);
}

// Round 4
// 327.017 us; speedup vs baseline: 1.3306x; 1.0948x over previous
//
#include <hip/hip_runtime.h>
#include <math.h>

#define NB 16
#define NN 1000
#define NT 16000          // NB*NN total nodes
#define NE 16000          // edges per graph
#define EBASE 256000      // NB*NE
#define ETOT 272000       // EBASE + NT self loops
#define F1 1024           // H1*C1
#define EMB 64
#define HID 128
#define KTOT 64000        // N*EMB mlp1 reduction length

typedef unsigned short ushort_t;
typedef unsigned int uint_t;
typedef __attribute__((ext_vector_type(8))) _Float16 half8;
typedef __attribute__((ext_vector_type(4))) float float4_;
typedef __attribute__((ext_vector_type(2))) float float2_;

// ---- scrambled edge mapping (faithful to reference row-major reshape) ----
__device__ __forceinline__ int src_of(const int* ei, int j) {
    if (j < EBASE) return ei[j] + (j / 32000) * 1000;
    return j - EBASE;
}
__device__ __forceinline__ int dst_of(const int* ei, int j) {
    if (j < EBASE) return ei[EBASE + j] + (8 + j / 32000) * 1000;
    return j - EBASE;
}

__device__ __forceinline__ float lrelu02(float r) { return r >= 0.f ? r : 0.2f * r; }
__device__ __forceinline__ float elu1(float v)    { return v > 0.f ? v : expm1f(v); }
__device__ __forceinline__ ushort_t f2h(float f) {
    _Float16 h = (_Float16)f;           // v_cvt_f16_f32, RTE
    union { _Float16 h; ushort_t u; } c; c.h = h; return c.u;
}

// ---- precontract attention vectors: wa[3][8] for conv1, v2[1024] for conv2 ----
__global__ void k_precompute(const float* __restrict__ W1, const float* __restrict__ as1w,
                             const float* __restrict__ ad1w, const float* __restrict__ W2,
                             const float* __restrict__ as2w, const float* __restrict__ ad2w,
                             float* wa_s, float* wa_d, float* v2s, float* v2d) {
    int t = threadIdx.x;
    float s = 0.f, d = 0.f;
    for (int c = 0; c < EMB; ++c) {
        float w = W2[t * EMB + c];
        s += w * as2w[c]; d += w * ad2w[c];
    }
    v2s[t] = s; v2d[t] = d;
    if (t < 24) {
        int k = t / 8, h = t % 8;
        float ss = 0.f, dd = 0.f;
        for (int c = 0; c < 128; ++c) {
            float w = W1[k * F1 + h * 128 + c];
            ss += w * as1w[h * 128 + c];
            dd += w * ad1w[h * 128 + c];
        }
        wa_s[k * 8 + h] = ss; wa_d[k * 8 + h] = dd;
    }
}

// ---- W2 transpose + fp16 cast: w2t[n][k], n<64, k<1024 ----
__global__ __launch_bounds__(256) void k_w2t(const float* __restrict__ W2,
                                             ushort_t* __restrict__ w2t) {
    __shared__ float tile[64][65];
    int k0 = blockIdx.x * 64;
    int t = threadIdx.x;
    int c = t & 63, g = t >> 6;
    for (int r = g; r < 64; r += 4)
        tile[r][c] = W2[(size_t)(k0 + r) * 64 + c];
    __syncthreads();
    int kk = t & 63, g2 = t >> 6;
    for (int n = g2; n < 64; n += 4)
        w2t[(size_t)n * 1024 + k0 + kk] = f2h(tile[kk][n]);
}

// ---- build x4[NT][4] and per-node attention logits a_src1/a_dst1 [NT][8] ----
__global__ void k_nodeinit(const float* __restrict__ actions, const float* __restrict__ nf,
                           const float* __restrict__ wa_s, const float* __restrict__ wa_d,
                           float* __restrict__ x4, float* __restrict__ as1, float* __restrict__ ad1) {
    int n = blockIdx.x * blockDim.x + threadIdx.x;
    if (n >= NT) return;
    float x0 = actions[n * 2 + 0];
    float x1v = actions[n * 2 + 1];
    float x2v = nf[n];
    float4_ xv = {x0, x1v, x2v, 0.f};
    *(float4_*)(x4 + (size_t)n * 4) = xv;
    #pragma unroll
    for (int h = 0; h < 8; ++h) {
        as1[n * 8 + h] = x0 * wa_s[h] + x1v * wa_s[8 + h] + x2v * wa_s[16 + h];
        ad1[n * 8 + h] = x0 * wa_d[h] + x1v * wa_d[8 + h] + x2v * wa_d[16 + h];
    }
}

// ---- CSR by dst: count / scan / fill ----
__global__ void k_count(const int* __restrict__ ei, int* __restrict__ counts) {
    int j = blockIdx.x * blockDim.x + threadIdx.x;
    if (j >= ETOT) return;
    atomicAdd(&counts[dst_of(ei, j)], 1);
}

__global__ __launch_bounds__(1024) void k_scan(const int* __restrict__ counts,
                                               int* __restrict__ offs, int* __restrict__ cursor) {
    __shared__ int lds[1024];
    int t = threadIdx.x;
    int base = t * 16;
    int local[16];
    int mysum = 0;
    #pragma unroll
    for (int i = 0; i < 16; ++i) {
        int idx = base + i;
        int c = (idx < NT) ? counts[idx] : 0;
        local[i] = c; mysum += c;
    }
    lds[t] = mysum;
    __syncthreads();
    for (int off = 1; off < 1024; off <<= 1) {
        int v = (t >= off) ? lds[t - off] : 0;
        __syncthreads();
        lds[t] += v;
        __syncthreads();
    }
    int run = lds[t] - mysum;
    #pragma unroll
    for (int i = 0; i < 16; ++i) {
        int idx = base + i;
        if (idx < NT) { offs[idx] = run; cursor[idx] = run; run += local[i]; }
    }
    if (t == 1023) offs[NT] = lds[1023];
}

__global__ void k_fill(const int* __restrict__ ei, int* __restrict__ cursor, int* __restrict__ esrc) {
    int j = blockIdx.x * blockDim.x + threadIdx.x;
    if (j >= ETOT) return;
    int dv = dst_of(ei, j);
    int pos = atomicAdd(&cursor[dv], 1);
    esrc[pos] = src_of(ei, j);
}

// ---- conv1: 4 nodes per wave, 16 lanes/node = (2 edge-slots x 8 heads) ----
// No max-subtraction (logits bounded |a|<~3; exp-safe; mathematically identical).
__global__ __launch_bounds__(64) void k_conv1(
    const int* __restrict__ offs, const int* __restrict__ esrc, const float* __restrict__ x4,
    const float* __restrict__ as1, const float* __restrict__ ad1,
    const float* __restrict__ W1, const float* __restrict__ b1,
    const float* __restrict__ v2s, const float* __restrict__ v2d,
    ushort_t* __restrict__ x1h, float* __restrict__ a2s, float* __restrict__ a2d) {
    int lane = threadIdx.x;
    int g = lane >> 4, lg = lane & 15;
    int eslot = lg >> 3, h = lg & 7;
    int d = blockIdx.x * 4 + g;
    int off = offs[d], end = offs[d + 1];
    float adv = ad1[d * 8 + h];

    float den = 0.f, s0 = 0.f, s1 = 0.f, s2 = 0.f;
    for (int e = off + eslot; e < end; e += 2) {
        int s = esrc[e];
        float ea = __expf(lrelu02(as1[s * 8 + h] + adv));
        float4_ xv = *(const float4_*)(x4 + (size_t)s * 4);
        den += ea; s0 += ea * xv.x; s1 += ea * xv.y; s2 += ea * xv.z;
    }
    // reduce over the 2 edge slots (xor 8 stays within the 16-lane group)
    den += __shfl_xor(den, 8, 64);
    s0  += __shfl_xor(s0, 8, 64);
    s1  += __shfl_xor(s1, 8, 64);
    s2  += __shfl_xor(s2, 8, 64);
    float inv = 1.f / den;
    float b0x = s0 * inv, b1x = s1 * inv, b2x = s2 * inv;

    // epilogue: 1024 channels / 16 lanes = 64 per lane, 2 at a time
    float acc_s = 0.f, acc_d = 0.f;
    uint_t* x1row = (uint_t*)(x1h + (size_t)d * F1);
    #pragma unroll
    for (int hh = 0; hh < 8; ++hh) {
        int srcl = (g << 4) + hh;
        float c0 = __shfl(b0x, srcl, 64);
        float c1 = __shfl(b1x, srcl, 64);
        float c2 = __shfl(b2x, srcl, 64);
        #pragma unroll
        for (int ii = 0; ii < 4; ++ii) {
            int idx = (hh * 4 + ii) * 32 + lg * 2;    // even channel index
            float2_ w0 = *(const float2_*)(W1 + idx);
            float2_ w1r = *(const float2_*)(W1 + F1 + idx);
            float2_ w2r = *(const float2_*)(W1 + 2 * F1 + idx);
            float2_ bb = *(const float2_*)(b1 + idx);
            float2_ vs = *(const float2_*)(v2s + idx);
            float2_ vd = *(const float2_*)(v2d + idx);
            float v0 = c0 * w0.x + c1 * w1r.x + c2 * w2r.x + bb.x;
            float v1 = c0 * w0.y + c1 * w1r.y + c2 * w2r.y + bb.y;
            v0 = elu1(v0); v1 = elu1(v1);
            acc_s += v0 * vs.x + v1 * vs.y;
            acc_d += v0 * vd.x + v1 * vd.y;
            x1row[idx >> 1] = (uint_t)f2h(v0) | ((uint_t)f2h(v1) << 16);
        }
    }
    // reduce acc over the 16-lane group
    #pragma unroll
    for (int st = 1; st < 16; st <<= 1) {
        acc_s += __shfl_xor(acc_s, st, 64);
        acc_d += __shfl_xor(acc_d, st, 64);
    }
    if (lg == 0) { a2s[d] = acc_s; a2d[d] = acc_d; }
}

// ---- h2 = x1 @ W2 via fp16 MFMA: [16000,1024]@[1024,64] -> fp32 ----
__global__ __launch_bounds__(256) void k_h2(const ushort_t* __restrict__ x1h,
                                            const ushort_t* __restrict__ w2t,
                                            float* __restrict__ h2) {
    int wave = threadIdx.x >> 6, lane = threadIdx.x & 63;
    int row0 = blockIdx.x * 64 + wave * 16;
    int mrow = lane & 15, kg = lane >> 4;
    const ushort_t* ap = x1h + (size_t)(row0 + mrow) * F1 + kg * 8;
    const ushort_t* bp = w2t + (size_t)mrow * F1 + kg * 8;
    float4_ acc[4] = {{0,0,0,0},{0,0,0,0},{0,0,0,0},{0,0,0,0}};
    #pragma unroll 4
    for (int ks = 0; ks < F1; ks += 32) {
        half8 a = *(const half8*)(ap + ks);
        #pragma unroll
        for (int t = 0; t < 4; ++t) {
            half8 b = *(const half8*)(bp + (size_t)t * 16 * F1 + ks);
            acc[t] = __builtin_amdgcn_mfma_f32_16x16x32_f16(a, b, acc[t], 0, 0, 0);
        }
    }
    int col = lane & 15;
    #pragma unroll
    for (int t = 0; t < 4; ++t) {
        #pragma unroll
        for (int r = 0; r < 4; ++r) {
            int row = kg * 4 + r;
            h2[(size_t)(row0 + row) * EMB + t * 16 + col] = acc[t][r];
        }
    }
}

// ---- conv2: fused softmax+message (no max pass); 4 edge slots x 16 ch-groups ----
// x2t layout: x2t[(n*64+c)*16 + b]  where node d = b*1000+n  (mlp1 k = n*64+c)
__global__ __launch_bounds__(64) void k_conv2(
    const int* __restrict__ offs, const int* __restrict__ esrc, const float* __restrict__ h2,
    const float* __restrict__ a2s, const float* __restrict__ a2d, const float* __restrict__ b2,
    float* __restrict__ x2t) {
    int d = blockIdx.x, lane = threadIdx.x;
    int off = offs[d], end = offs[d + 1];
    float adv = a2d[d];
    int eg = lane >> 4, c4 = (lane & 15) * 4;

    float den = 0.f;
    float4_ acc = {0.f, 0.f, 0.f, 0.f};
    for (int e = off + eg; e < end; e += 4) {
        int s = esrc[e];
        float ea = __expf(lrelu02(a2s[s] + adv));
        float4_ hv = *(const float4_*)(h2 + (size_t)s * EMB + c4);
        den += ea;
        acc.x += ea * hv.x; acc.y += ea * hv.y; acc.z += ea * hv.z; acc.w += ea * hv.w;
    }
    #pragma unroll
    for (int st = 16; st < 64; st <<= 1) {
        den   += __shfl_xor(den, st, 64);
        acc.x += __shfl_xor(acc.x, st, 64);
        acc.y += __shfl_xor(acc.y, st, 64);
        acc.z += __shfl_xor(acc.z, st, 64);
        acc.w += __shfl_xor(acc.w, st, 64);
    }
    if (eg == 0) {
        float inv = 1.f / den;
        int n = d % NN, b = d / NN;
        #pragma unroll
        for (int q = 0; q < 4; ++q) {
            float v = acc[q] * inv + b2[c4 + q];
            x2t[(size_t)(n * EMB + c4 + q) * NB + b] = elu1(v);
        }
    }
}

// ---- MLP1 stage A: per-wave row-parallel; 512 blocks x 256 threads ----
// wave handles w1 row k (64 lanes x float2 = full 128-col row), k strided 2048
__global__ __launch_bounds__(256) void k_mlp1(const float* __restrict__ x2t,
                                              const float* __restrict__ w1,
                                              float* __restrict__ y1part) {
    __shared__ float red[NB * HID];
    int t = threadIdx.x;
    int wave = t >> 6, lane = t & 63;
    int j2 = lane * 2;
    float2_ acc[NB];
    #pragma unroll
    for (int b = 0; b < NB; ++b) acc[b] = (float2_){0.f, 0.f};

    for (int k = blockIdx.x * 4 + wave; k < KTOT; k += 2048) {
        int kk = __builtin_amdgcn_readfirstlane(k);
        float2_ w = *(const float2_*)(w1 + (size_t)kk * HID + j2);
        const float* xr = x2t + (size_t)kk * NB;    // uniform -> s_load
        #pragma unroll
        for (int b = 0; b < NB; ++b) {
            float xv = xr[b];
            acc[b].x += xv * w.x;
            acc[b].y += xv * w.y;
        }
    }
    // block-reduce 4 waves via LDS (sequential add, 4 barriers)
    for (int w = 0; w < 4; ++w) {
        if (wave == w) {
            #pragma unroll
            for (int b = 0; b < NB; ++b) {
                if (w == 0) {
                    red[b * HID + j2]     = acc[b].x;
                    red[b * HID + j2 + 1] = acc[b].y;
                } else {
                    red[b * HID + j2]     += acc[b].x;
                    red[b * HID + j2 + 1] += acc[b].y;
                }
            }
        }
        __syncthreads();
    }
    float* yp = y1part + (size_t)blockIdx.x * (NB * HID);
    for (int idx = t; idx < NB * HID; idx += 256)
        yp[idx] = red[idx];
}

// ---- MLP1 stage B: reduce 512 partials -> y1sum (atomic, 16K adds) ----
__global__ __launch_bounds__(256) void k_mlp1b(const float* __restrict__ y1part,
                                               float* __restrict__ y1sum) {
    int b = blockIdx.x;
    int pc = b >> 3, oc = b & 7;      // 8 p-chunks of 64, 8 out-chunks of 256
    int idx = oc * 256 + threadIdx.x;
    float s = 0.f;
    #pragma unroll 4
    for (int p = pc * 64; p < pc * 64 + 64; ++p)
        s += y1part[(size_t)p * (NB * HID) + idx];
    atomicAdd(&y1sum[idx], s);
}

// ---- MLP2: relu(y1sum+b1), then y2 = relu(y1 @ w2 + b2) ----
__global__ __launch_bounds__(256) void k_mlp2(const float* __restrict__ y1sum,
                                              const float* __restrict__ b1m,
                                              const float* __restrict__ w2,
                                              const float* __restrict__ b2m,
                                              float* __restrict__ y2) {
    __shared__ float y1[NB * HID];
    int t = threadIdx.x;
    for (int idx = t; idx < NB * HID; idx += 256)
        y1[idx] = fmaxf(y1sum[idx] + b1m[idx & 127], 0.f);
    __syncthreads();
    #pragma unroll
    for (int i = 0; i < 8; ++i) {
        int o = t + i * 256;
        int b = o >> 7, j = o & 127;
        float acc = b2m[j];
        for (int k = 0; k < HID; ++k) acc += y1[b * HID + k] * w2[k * HID + j];
        y2[o] = fmaxf(acc, 0.f);
    }
}

// ---- output: sigmoid(y2 @ out_w + out_b) -> [16,1000] ----
__global__ __launch_bounds__(64) void k_out(const float* __restrict__ y2,
                                            const float* __restrict__ ow,
                                            const float* __restrict__ ob,
                                            float* __restrict__ out) {
    int n = blockIdx.x * 64 + threadIdx.x;
    if (n >= NN) return;
    float acc[NB];
    #pragma unroll
    for (int b = 0; b < NB; ++b) acc[b] = 0.f;
    for (int jj = 0; jj < HID; ++jj) {
        float w = ow[jj * NN + n];
        #pragma unroll
        for (int b = 0; b < NB; ++b) acc[b] += y2[b * HID + jj] * w;
    }
    float obv = ob[n];
    #pragma unroll
    for (int b = 0; b < NB; ++b)
        out[b * NN + n] = 1.f / (1.f + __expf(-(acc[b] + obv)));
}

extern "C" void kernel_launch(void* const* d_in, const int* in_sizes, int n_in,
                              void* d_out, int out_size, void* d_ws, size_t ws_size,
                              hipStream_t stream) {
    const float* actions = (const float*)d_in[0];
    const float* nf      = (const float*)d_in[1];
    const int*   ei      = (const int*)d_in[2];
    const float* W1      = (const float*)d_in[3];
    const float* as1w    = (const float*)d_in[4];
    const float* ad1w    = (const float*)d_in[5];
    const float* b1      = (const float*)d_in[6];
    const float* W2      = (const float*)d_in[7];
    const float* as2w    = (const float*)d_in[8];
    const float* ad2w    = (const float*)d_in[9];
    const float* b2      = (const float*)d_in[10];
    const float* mw1     = (const float*)d_in[11];
    const float* mb1     = (const float*)d_in[12];
    const float* mw2     = (const float*)d_in[13];
    const float* mb2     = (const float*)d_in[14];
    const float* ow      = (const float*)d_in[15];
    const float* ob      = (const float*)d_in[16];
    float* out = (float*)d_out;

    // workspace carve (all segments 16B-aligned)
    float* f = (float*)d_ws;
    float* x4    = f;  f += (size_t)NT * 4;
    float* h2    = f;  f += (size_t)NT * EMB;
    float* x2t   = f;  f += (size_t)NT * EMB;
    float* as1   = f;  f += NT * 8;
    float* ad1   = f;  f += NT * 8;
    float* a2s   = f;  f += NT;
    float* a2d   = f;  f += NT;
    float* wa_s  = f;  f += 32;
    float* wa_d  = f;  f += 32;
    float* v2s   = f;  f += F1;
    float* v2d   = f;  f += F1;
    float* y1part= f;  f += (size_t)512 * NB * HID;
    float* y1sum = f;  f += NB * HID;
    float* y2    = f;  f += NB * HID;
    ushort_t* x1h = (ushort_t*)f;
    ushort_t* w2t = x1h + (size_t)NT * F1;
    int* ip = (int*)(w2t + (size_t)EMB * F1);
    int* counts = ip; ip += NT;
    int* offs   = ip; ip += NT + 1;
    int* cursor = ip; ip += NT;
    int* esrc   = ip; ip += ETOT;

    hipMemsetAsync(counts, 0, NT * sizeof(int), stream);
    hipMemsetAsync(y1sum, 0, NB * HID * sizeof(float), stream);

    k_precompute<<<1, 1024, 0, stream>>>(W1, as1w, ad1w, W2, as2w, ad2w, wa_s, wa_d, v2s, v2d);
    k_w2t<<<16, 256, 0, stream>>>(W2, w2t);
    k_nodeinit<<<(NT + 255) / 256, 256, 0, stream>>>(actions, nf, wa_s, wa_d, x4, as1, ad1);
    k_count<<<(ETOT + 255) / 256, 256, 0, stream>>>(ei, counts);
    k_scan<<<1, 1024, 0, stream>>>(counts, offs, cursor);
    k_fill<<<(ETOT + 255) / 256, 256, 0, stream>>>(ei, cursor, esrc);
    k_conv1<<<NT / 4, 64, 0, stream>>>(offs, esrc, x4, as1, ad1, W1, b1, v2s, v2d, x1h, a2s, a2d);
    k_h2<<<NT / 64, 256, 0, stream>>>(x1h, w2t, h2);
    k_conv2<<<NT, 64, 0, stream>>>(offs, esrc, h2, a2s, a2d, b2, x2t);
    k_mlp1<<<512, 256, 0, stream>>>(x2t, mw1, y1part);
    k_mlp1b<<<64, 256, 0, stream>>>(y1part, y1sum);
    k_mlp2<<<1, 256, 0, stream>>>(y1sum, mb1, mw2, mb2, y2);
    k_out<<<(NN + 63) / 64, 64, 0, stream>>>(y2, ow, ob, out);
}

// Round 5
// 298.004 us; speedup vs baseline: 1.4602x; 1.0974x over previous
//
#include <hip/hip_runtime.h>
#include <math.h>

#define NB 16
#define NN 1000
#define NT 16000          // NB*NN total nodes
#define NE 16000          // edges per graph
#define EBASE 256000      // NB*NE
#define ETOT 272000       // EBASE + NT self loops
#define F1 1024           // H1*C1
#define EMB 64
#define HID 128
#define KTOT 64000        // N*EMB mlp1 reduction length

typedef unsigned short ushort_t;
typedef unsigned int uint_t;
typedef __attribute__((ext_vector_type(8))) _Float16 half8;
typedef __attribute__((ext_vector_type(4))) float float4_;
typedef __attribute__((ext_vector_type(2))) float float2_;
typedef __attribute__((ext_vector_type(2))) uint_t uint2_;

// ---- scrambled edge mapping (faithful to reference row-major reshape) ----
__device__ __forceinline__ int src_of(const int* ei, int j) {
    if (j < EBASE) return ei[j] + (j / 32000) * 1000;
    return j - EBASE;
}
__device__ __forceinline__ int dst_of(const int* ei, int j) {
    if (j < EBASE) return ei[EBASE + j] + (8 + j / 32000) * 1000;
    return j - EBASE;
}

__device__ __forceinline__ float lrelu02(float r) { return r >= 0.f ? r : 0.2f * r; }
__device__ __forceinline__ float elu1(float v)    { return v > 0.f ? v : expm1f(v); }
__device__ __forceinline__ ushort_t f2h(float f) {
    _Float16 h = (_Float16)f;           // v_cvt_f16_f32, RTE
    union { _Float16 h; ushort_t u; } c; c.h = h; return c.u;
}

// ==== kernel A: fused {edge count | wa precompute | W2 transpose+fp16} ====
__global__ __launch_bounds__(256) void k_prep(
    const int* __restrict__ ei, int* __restrict__ counts,
    const float* __restrict__ W1, const float* __restrict__ as1w, const float* __restrict__ ad1w,
    const float* __restrict__ W2, float* __restrict__ wa_s, float* __restrict__ wa_d,
    ushort_t* __restrict__ w2t) {
    __shared__ float tile[64][65];
    int blk = blockIdx.x, t = threadIdx.x;
    if (blk < 1063) {                       // edge count (CSR histogram)
        int j = blk * 256 + t;
        if (j < ETOT) atomicAdd(&counts[dst_of(ei, j)], 1);
    } else if (blk == 1063) {               // wa[3][8] precontract for conv1 logits
        if (t < 24) {
            int k = t / 8, h = t % 8;
            float ss = 0.f, dd = 0.f;
            for (int c = 0; c < 128; ++c) {
                float w = W1[k * F1 + h * 128 + c];
                ss += w * as1w[h * 128 + c];
                dd += w * ad1w[h * 128 + c];
            }
            wa_s[k * 8 + h] = ss; wa_d[k * 8 + h] = dd;
        }
    } else {                                // W2 transpose + fp16: w2t[n][k]
        int k0 = (blk - 1064) * 64;
        int c = t & 63, g = t >> 6;
        for (int r = g; r < 64; r += 4)
            tile[r][c] = W2[(size_t)(k0 + r) * 64 + c];
        __syncthreads();
        for (int n = g; n < 64; n += 4)
            w2t[(size_t)n * 1024 + k0 + c] = f2h(tile[c][n]);
    }
}

// ==== kernel B: fused {CSR scan | nodeinit (x4 + conv1 logits)} ====
__global__ __launch_bounds__(1024) void k_prep2(
    const float* __restrict__ actions, const float* __restrict__ nf,
    const float* __restrict__ wa_s, const float* __restrict__ wa_d,
    float* __restrict__ x4, float* __restrict__ as1, float* __restrict__ ad1,
    const int* __restrict__ counts, int* __restrict__ offs, int* __restrict__ cursor) {
    __shared__ int lds[1024];
    int t = threadIdx.x;
    if (blockIdx.x == 0) {                  // exclusive scan of counts -> offs/cursor
        int base = t * 16;
        int local[16];
        int mysum = 0;
        #pragma unroll
        for (int i = 0; i < 16; ++i) {
            int idx = base + i;
            int c = (idx < NT) ? counts[idx] : 0;
            local[i] = c; mysum += c;
        }
        lds[t] = mysum;
        __syncthreads();
        for (int off = 1; off < 1024; off <<= 1) {
            int v = (t >= off) ? lds[t - off] : 0;
            __syncthreads();
            lds[t] += v;
            __syncthreads();
        }
        int run = lds[t] - mysum;
        #pragma unroll
        for (int i = 0; i < 16; ++i) {
            int idx = base + i;
            if (idx < NT) { offs[idx] = run; cursor[idx] = run; run += local[i]; }
        }
        if (t == 1023) offs[NT] = lds[1023];
    } else {                                // nodeinit: 1000 nodes per block
        int n = (blockIdx.x - 1) * 1000 + t;
        if (t < 1000) {
            float x0 = actions[n * 2 + 0];
            float x1v = actions[n * 2 + 1];
            float x2v = nf[n];
            float4_ xv = {x0, x1v, x2v, 0.f};
            *(float4_*)(x4 + (size_t)n * 4) = xv;
            #pragma unroll
            for (int h = 0; h < 8; ++h) {
                as1[n * 8 + h] = x0 * wa_s[h] + x1v * wa_s[8 + h] + x2v * wa_s[16 + h];
                ad1[n * 8 + h] = x0 * wa_d[h] + x1v * wa_d[8 + h] + x2v * wa_d[16 + h];
            }
        }
    }
}

// ==== kernel C: CSR fill ====
__global__ void k_fill(const int* __restrict__ ei, int* __restrict__ cursor, int* __restrict__ esrc) {
    int j = blockIdx.x * blockDim.x + threadIdx.x;
    if (j >= ETOT) return;
    int dv = dst_of(ei, j);
    int pos = atomicAdd(&cursor[dv], 1);
    esrc[pos] = src_of(ei, j);
}

// ==== conv1: 16 nodes/block. Phase A: edge softmax (wave=4 nodes, 16 lanes/node).
//      Phase B: channel-parallel epilogue, W1/b1 slice in registers. ====
__global__ __launch_bounds__(256) void k_conv1(
    const int* __restrict__ offs, const int* __restrict__ esrc, const float* __restrict__ x4,
    const float* __restrict__ as1, const float* __restrict__ ad1,
    const float* __restrict__ W1, const float* __restrict__ b1,
    ushort_t* __restrict__ x1h) {
    __shared__ float smb[16][8][3];
    int t = threadIdx.x;
    int wave = t >> 6, lane = t & 63;
    // per-thread weight registers: channels t*4 .. t*4+3 (loaded once)
    float4_ w0 = *(const float4_*)(W1 + t * 4);
    float4_ w1r = *(const float4_*)(W1 + F1 + t * 4);
    float4_ w2r = *(const float4_*)(W1 + 2 * F1 + t * 4);
    float4_ bb = *(const float4_*)(b1 + t * 4);

    // phase A
    int g = lane >> 4, lg = lane & 15, eslot = lg >> 3, h = lg & 7;
    int nd0 = wave * 4 + g;
    int d = blockIdx.x * 16 + nd0;
    int off = offs[d], end = offs[d + 1];
    float adv = ad1[d * 8 + h];
    float den = 0.f, s0 = 0.f, s1 = 0.f, s2 = 0.f;
    for (int e = off + eslot; e < end; e += 2) {
        int s = esrc[e];
        float ea = __expf(lrelu02(as1[s * 8 + h] + adv));
        float4_ xv = *(const float4_*)(x4 + (size_t)s * 4);
        den += ea; s0 += ea * xv.x; s1 += ea * xv.y; s2 += ea * xv.z;
    }
    den += __shfl_xor(den, 8, 64);
    s0  += __shfl_xor(s0, 8, 64);
    s1  += __shfl_xor(s1, 8, 64);
    s2  += __shfl_xor(s2, 8, 64);
    if (eslot == 0) {
        float inv = 1.f / den;
        smb[nd0][h][0] = s0 * inv;
        smb[nd0][h][1] = s1 * inv;
        smb[nd0][h][2] = s2 * inv;
    }
    __syncthreads();

    // phase B: thread t -> channels 4t..4t+3, head hh = t>>5 (fixed per thread)
    int hh = t >> 5;
    uint2_* xr = (uint2_*)(x1h + (size_t)blockIdx.x * 16 * F1 + t * 4);
    #pragma unroll 4
    for (int nd = 0; nd < 16; ++nd) {
        float c0 = smb[nd][hh][0], c1 = smb[nd][hh][1], c2 = smb[nd][hh][2];
        float v0 = c0 * w0.x + c1 * w1r.x + c2 * w2r.x + bb.x;
        float v1 = c0 * w0.y + c1 * w1r.y + c2 * w2r.y + bb.y;
        float v2 = c0 * w0.z + c1 * w1r.z + c2 * w2r.z + bb.z;
        float v3 = c0 * w0.w + c1 * w1r.w + c2 * w2r.w + bb.w;
        v0 = elu1(v0); v1 = elu1(v1); v2 = elu1(v2); v3 = elu1(v3);
        uint2_ p;
        p.x = (uint_t)f2h(v0) | ((uint_t)f2h(v1) << 16);
        p.y = (uint_t)f2h(v2) | ((uint_t)f2h(v3) << 16);
        xr[(size_t)nd * (F1 / 4)] = p;
    }
}

// ==== h2 = x1 @ W2 via fp16 MFMA + fused a2s/a2d = h2 . att2 epilogue ====
__global__ __launch_bounds__(256) void k_h2(const ushort_t* __restrict__ x1h,
                                            const ushort_t* __restrict__ w2t,
                                            const float* __restrict__ as2w,
                                            const float* __restrict__ ad2w,
                                            float* __restrict__ h2,
                                            float* __restrict__ a2s, float* __restrict__ a2d) {
    int wave = threadIdx.x >> 6, lane = threadIdx.x & 63;
    int row0 = blockIdx.x * 64 + wave * 16;
    int col = lane & 15, kg = lane >> 4;
    const ushort_t* ap = x1h + (size_t)(row0 + col) * F1 + kg * 8;
    const ushort_t* bp = w2t + (size_t)col * F1 + kg * 8;
    float4_ acc[4] = {{0,0,0,0},{0,0,0,0},{0,0,0,0},{0,0,0,0}};
    #pragma unroll 4
    for (int ks = 0; ks < F1; ks += 32) {
        half8 a = *(const half8*)(ap + ks);
        #pragma unroll
        for (int t4 = 0; t4 < 4; ++t4) {
            half8 b = *(const half8*)(bp + (size_t)t4 * 16 * F1 + ks);
            acc[t4] = __builtin_amdgcn_mfma_f32_16x16x32_f16(a, b, acc[t4], 0, 0, 0);
        }
    }
    // store h2 (C/D layout: row = kg*4+r, col-channel = t4*16+col)
    #pragma unroll
    for (int t4 = 0; t4 < 4; ++t4) {
        #pragma unroll
        for (int r = 0; r < 4; ++r)
            h2[(size_t)(row0 + kg * 4 + r) * EMB + t4 * 16 + col] = acc[t4][r];
    }
    // a2s/a2d epilogue: dot over 64 channels (t4 in regs, col across 16 lanes)
    float ps[4] = {0.f, 0.f, 0.f, 0.f}, pd[4] = {0.f, 0.f, 0.f, 0.f};
    #pragma unroll
    for (int t4 = 0; t4 < 4; ++t4) {
        float sw = as2w[t4 * 16 + col];
        float dw = ad2w[t4 * 16 + col];
        #pragma unroll
        for (int r = 0; r < 4; ++r) {
            ps[r] += acc[t4][r] * sw;
            pd[r] += acc[t4][r] * dw;
        }
    }
    #pragma unroll
    for (int st = 1; st < 16; st <<= 1) {
        #pragma unroll
        for (int r = 0; r < 4; ++r) {
            ps[r] += __shfl_xor(ps[r], st, 64);
            pd[r] += __shfl_xor(pd[r], st, 64);
        }
    }
    if (col == 0) {
        #pragma unroll
        for (int r = 0; r < 4; ++r) {
            a2s[row0 + kg * 4 + r] = ps[r];
            a2d[row0 + kg * 4 + r] = pd[r];
        }
    }
}

// ==== conv2: fused softmax+message; 4 nodes/block (wave/node) ====
// x2t layout: x2t[(n*64+c)*16 + b]  where node d = b*1000+n  (mlp1 k = n*64+c)
__global__ __launch_bounds__(256) void k_conv2(
    const int* __restrict__ offs, const int* __restrict__ esrc, const float* __restrict__ h2,
    const float* __restrict__ a2s, const float* __restrict__ a2d, const float* __restrict__ b2,
    float* __restrict__ x2t) {
    int t = threadIdx.x;
    int wave = t >> 6, lane = t & 63;
    int d = blockIdx.x * 4 + wave;
    int off = offs[d], end = offs[d + 1];
    float adv = a2d[d];
    int eg = lane >> 4, c4 = (lane & 15) * 4;

    float den = 0.f;
    float4_ acc = {0.f, 0.f, 0.f, 0.f};
    for (int e = off + eg; e < end; e += 4) {
        int s = esrc[e];
        float ea = __expf(lrelu02(a2s[s] + adv));
        float4_ hv = *(const float4_*)(h2 + (size_t)s * EMB + c4);
        den += ea;
        acc.x += ea * hv.x; acc.y += ea * hv.y; acc.z += ea * hv.z; acc.w += ea * hv.w;
    }
    #pragma unroll
    for (int st = 16; st < 64; st <<= 1) {
        den   += __shfl_xor(den, st, 64);
        acc.x += __shfl_xor(acc.x, st, 64);
        acc.y += __shfl_xor(acc.y, st, 64);
        acc.z += __shfl_xor(acc.z, st, 64);
        acc.w += __shfl_xor(acc.w, st, 64);
    }
    if (eg == 0) {
        float inv = 1.f / den;
        int n = d % NN, b = d / NN;
        #pragma unroll
        for (int q = 0; q < 4; ++q) {
            float v = acc[q] * inv + b2[c4 + q];
            x2t[(size_t)(n * EMB + c4 + q) * NB + b] = elu1(v);
        }
    }
}

// ==== MLP1 stage A: per-wave row-parallel; 512 blocks x 256 threads ====
__global__ __launch_bounds__(256) void k_mlp1(const float* __restrict__ x2t,
                                              const float* __restrict__ w1,
                                              float* __restrict__ y1part) {
    __shared__ float red[NB * HID];
    int t = threadIdx.x;
    int wave = t >> 6, lane = t & 63;
    int j2 = lane * 2;
    float2_ acc[NB];
    #pragma unroll
    for (int b = 0; b < NB; ++b) acc[b] = (float2_){0.f, 0.f};

    for (int k = blockIdx.x * 4 + wave; k < KTOT; k += 2048) {
        int kk = __builtin_amdgcn_readfirstlane(k);
        float2_ w = *(const float2_*)(w1 + (size_t)kk * HID + j2);
        const float* xr = x2t + (size_t)kk * NB;    // uniform -> s_load
        #pragma unroll
        for (int b = 0; b < NB; ++b) {
            float xv = xr[b];
            acc[b].x += xv * w.x;
            acc[b].y += xv * w.y;
        }
    }
    for (int w = 0; w < 4; ++w) {
        if (wave == w) {
            #pragma unroll
            for (int b = 0; b < NB; ++b) {
                if (w == 0) {
                    red[b * HID + j2]     = acc[b].x;
                    red[b * HID + j2 + 1] = acc[b].y;
                } else {
                    red[b * HID + j2]     += acc[b].x;
                    red[b * HID + j2 + 1] += acc[b].y;
                }
            }
        }
        __syncthreads();
    }
    float* yp = y1part + (size_t)blockIdx.x * (NB * HID);
    for (int idx = t; idx < NB * HID; idx += 256)
        yp[idx] = red[idx];
}

// ==== MLP1 stage B: reduce 512 partials -> y1sum ====
__global__ __launch_bounds__(256) void k_mlp1b(const float* __restrict__ y1part,
                                               float* __restrict__ y1sum) {
    int b = blockIdx.x;
    int pc = b >> 3, oc = b & 7;
    int idx = oc * 256 + threadIdx.x;
    float s = 0.f;
    #pragma unroll 4
    for (int p = pc * 64; p < pc * 64 + 64; ++p)
        s += y1part[(size_t)p * (NB * HID) + idx];
    atomicAdd(&y1sum[idx], s);
}

// ==== MLP2: relu(y1sum+b1), then y2 = relu(y1 @ w2 + b2) ====
__global__ __launch_bounds__(256) void k_mlp2(const float* __restrict__ y1sum,
                                              const float* __restrict__ b1m,
                                              const float* __restrict__ w2,
                                              const float* __restrict__ b2m,
                                              float* __restrict__ y2) {
    __shared__ float y1[NB * HID];
    int t = threadIdx.x;
    for (int idx = t; idx < NB * HID; idx += 256)
        y1[idx] = fmaxf(y1sum[idx] + b1m[idx & 127], 0.f);
    __syncthreads();
    #pragma unroll
    for (int i = 0; i < 8; ++i) {
        int o = t + i * 256;
        int b = o >> 7, j = o & 127;
        float acc = b2m[j];
        for (int k = 0; k < HID; ++k) acc += y1[b * HID + k] * w2[k * HID + j];
        y2[o] = fmaxf(acc, 0.f);
    }
}

// ==== output: sigmoid(y2 @ out_w + out_b) -> [16,1000] ====
__global__ __launch_bounds__(256) void k_out(const float* __restrict__ y2,
                                             const float* __restrict__ ow,
                                             const float* __restrict__ ob,
                                             float* __restrict__ out) {
    int n = blockIdx.x * 256 + threadIdx.x;
    if (n >= NN) return;
    float acc[NB];
    #pragma unroll
    for (int b = 0; b < NB; ++b) acc[b] = 0.f;
    for (int jj = 0; jj < HID; ++jj) {
        float w = ow[jj * NN + n];
        #pragma unroll
        for (int b = 0; b < NB; ++b) acc[b] += y2[b * HID + jj] * w;
    }
    float obv = ob[n];
    #pragma unroll
    for (int b = 0; b < NB; ++b)
        out[b * NN + n] = 1.f / (1.f + __expf(-(acc[b] + obv)));
}

extern "C" void kernel_launch(void* const* d_in, const int* in_sizes, int n_in,
                              void* d_out, int out_size, void* d_ws, size_t ws_size,
                              hipStream_t stream) {
    const float* actions = (const float*)d_in[0];
    const float* nf      = (const float*)d_in[1];
    const int*   ei      = (const int*)d_in[2];
    const float* W1      = (const float*)d_in[3];
    const float* as1w    = (const float*)d_in[4];
    const float* ad1w    = (const float*)d_in[5];
    const float* b1      = (const float*)d_in[6];
    const float* W2      = (const float*)d_in[7];
    const float* as2w    = (const float*)d_in[8];
    const float* ad2w    = (const float*)d_in[9];
    const float* b2      = (const float*)d_in[10];
    const float* mw1     = (const float*)d_in[11];
    const float* mb1     = (const float*)d_in[12];
    const float* mw2     = (const float*)d_in[13];
    const float* mb2     = (const float*)d_in[14];
    const float* ow      = (const float*)d_in[15];
    const float* ob      = (const float*)d_in[16];
    float* out = (float*)d_out;

    // workspace carve (all segments 16B-aligned)
    float* f = (float*)d_ws;
    float* x4    = f;  f += (size_t)NT * 4;
    float* h2    = f;  f += (size_t)NT * EMB;
    float* x2t   = f;  f += (size_t)NT * EMB;
    float* as1   = f;  f += NT * 8;
    float* ad1   = f;  f += NT * 8;
    float* a2s   = f;  f += NT;
    float* a2d   = f;  f += NT;
    float* wa_s  = f;  f += 32;
    float* wa_d  = f;  f += 32;
    float* y1part= f;  f += (size_t)512 * NB * HID;
    float* y1sum = f;  f += NB * HID;
    float* y2    = f;  f += NB * HID;
    ushort_t* x1h = (ushort_t*)f;
    ushort_t* w2t = x1h + (size_t)NT * F1;
    int* ip = (int*)(w2t + (size_t)EMB * F1);
    int* counts = ip; ip += NT;
    int* offs   = ip; ip += NT + 1;
    int* cursor = ip; ip += NT;
    int* esrc   = ip; ip += ETOT;

    hipMemsetAsync(counts, 0, NT * sizeof(int), stream);
    hipMemsetAsync(y1sum, 0, NB * HID * sizeof(float), stream);

    k_prep<<<1080, 256, 0, stream>>>(ei, counts, W1, as1w, ad1w, W2, wa_s, wa_d, w2t);
    k_prep2<<<17, 1024, 0, stream>>>(actions, nf, wa_s, wa_d, x4, as1, ad1, counts, offs, cursor);
    k_fill<<<(ETOT + 255) / 256, 256, 0, stream>>>(ei, cursor, esrc);
    k_conv1<<<NT / 16, 256, 0, stream>>>(offs, esrc, x4, as1, ad1, W1, b1, x1h);
    k_h2<<<NT / 64, 256, 0, stream>>>(x1h, w2t, as2w, ad2w, h2, a2s, a2d);
    k_conv2<<<NT / 4, 256, 0, stream>>>(offs, esrc, h2, a2s, a2d, b2, x2t);
    k_mlp1<<<512, 256, 0, stream>>>(x2t, mw1, y1part);
    k_mlp1b<<<64, 256, 0, stream>>>(y1part, y1sum);
    k_mlp2<<<1, 256, 0, stream>>>(y1sum, mb1, mw2, mb2, y2);
    k_out<<<4, 256, 0, stream>>>(y2, ow, ob, out);
}